// Round 1
// baseline (443.639 us; speedup 1.0000x reference)
//
#include <hip/hip_runtime.h>
#include <math.h>

typedef __attribute__((ext_vector_type(8))) short short8;
typedef __attribute__((ext_vector_type(4))) float floatx4;

#define NB    4
#define CIN   64
#define COUT  128
#define IMH   128
#define IMW   256
#define KTOT  576           // CIN * 9
#define NDESC (IMH * IMW * 9)
#define PXT   64            // pixel (column) tile per block
#define KC    64            // K-chunk (multiple of 32 for MFMA)

struct __align__(16) Desc {
  int o00, o01, o10, o11;     // clamped element offsets within one HxW plane
  float w00, w01, w10, w11;   // bilinear weights with validity masks folded in
};

__device__ __forceinline__ short f2bf(float f) {
  union { float f; unsigned u; } v; v.f = f;
  unsigned r = (v.u + 0x7FFFu + ((v.u >> 16) & 1u)) >> 16;  // RNE
  return (short)r;
}

// ---------------- kernel 1: spherical grid -> bilinear descriptors ----------
__global__ __launch_bounds__(256) void gen_desc_kernel(Desc* __restrict__ desc) {
  int idx = blockIdx.x * 256 + threadIdx.x;
  if (idx >= NDESC) return;
  int k  = idx % 9;
  int rc = idx / 9;
  int c  = rc % IMW;
  int r  = rc / IMW;
  int i = k / 3, j = k % 3;
  const double pi = 3.14159265358979323846;
  double dphi = pi / IMH;
  double dth  = 2.0 * pi / IMW;
  double t  = tan(dth);
  double p  = tan(dphi);
  double sp = p / cos(dth);
  double X = (j == 0) ? -t : ((j == 2) ? t : 0.0);
  double Y = 0.0;
  if (i == 0)      Y = (j == 1) ?  p :  sp;
  else if (i == 2) Y = (j == 1) ? -p : -sp;
  if (i == 1 && j == 1) { X = 1.0; Y = 1.0; }   // center (overridden below)
  double rho = sqrt(X * X + Y * Y);
  double v   = atan(rho);
  double phi   = -(((double)r + 0.5) / IMH * pi - pi * 0.5);
  double theta = ((double)c + 0.5) / IMW * (2.0 * pi) - pi;
  double sv = sin(v), cv = cos(v), sphi = sin(phi), cphi = cos(phi);
  double arg = cv * sphi + Y * sv * cphi / rho;
  arg = fmin(1.0, fmax(-1.0, arg));
  double new_phi = asin(arg);
  double denom = rho * cphi * cv - Y * sphi * sv;
  double new_theta = theta + atan(X * sv / denom);
  double new_r = (-new_phi + pi * 0.5) * IMH / pi - 0.5;
  double new_c = (new_theta + pi) * IMW / (2.0 * pi) - 0.5;
  new_c = fmod(new_c + (double)IMW, (double)IMW);
  if (i == 1 && j == 1) { new_r = (double)r; new_c = (double)c; }
  // exact reference roundtrip: double -> f32 normalized grid -> f32 unnormalize
  float gx = (float)(new_c * 2.0 / IMW - 1.0);
  float gy = (float)(new_r * 2.0 / IMH - 1.0);
  float ix = ((gx + 1.0f) * (float)IMW - 1.0f) * 0.5f;   // == new_c - 0.5
  float iy = ((gy + 1.0f) * (float)IMH - 1.0f) * 0.5f;   // == new_r - 0.5
  float fx = floorf(ix), fy = floorf(iy);
  int x0 = (int)fx, y0 = (int)fy;
  float wx1 = ix - fx, wy1 = iy - fy;
  float wx0 = 1.0f - wx1, wy0 = 1.0f - wy1;
  int x1 = x0 + 1, y1 = y0 + 1;
  bool vx0 = (x0 >= 0) & (x0 <= IMW - 1);
  bool vx1 = (x1 >= 0) & (x1 <= IMW - 1);
  bool vy0 = (y0 >= 0) & (y0 <= IMH - 1);
  bool vy1 = (y1 >= 0) & (y1 <= IMH - 1);
  int x0c = min(max(x0, 0), IMW - 1), x1c = min(max(x1, 0), IMW - 1);
  int y0c = min(max(y0, 0), IMH - 1), y1c = min(max(y1, 0), IMH - 1);
  Desc d;
  d.o00 = y0c * IMW + x0c;
  d.o01 = y0c * IMW + x1c;
  d.o10 = y1c * IMW + x0c;
  d.o11 = y1c * IMW + x1c;
  d.w00 = (vy0 & vx0) ? wy0 * wx0 : 0.0f;
  d.w01 = (vy0 & vx1) ? wy0 * wx1 : 0.0f;
  d.w10 = (vy1 & vx0) ? wy1 * wx0 : 0.0f;
  d.w11 = (vy1 & vx1) ? wy1 * wx1 : 0.0f;
  desc[idx] = d;
}

// ---------------- kernel 2: weight fp32 [co][ci][3][3] -> bf16 [K/8][co][8] --
__global__ __launch_bounds__(256) void prep_w_kernel(const float* __restrict__ w,
                                                     short* __restrict__ wbf) {
  int idx = blockIdx.x * 256 + threadIdx.x;   // COUT*KTOT = 73728
  if (idx >= COUT * KTOT) return;
  int co = idx / KTOT;
  int K  = idx - co * KTOT;                   // K = ci*9 + (kr*3+kc), contiguous in w
  float f = w[co * KTOT + K];
  wbf[(K >> 3) * (COUT * 8) + co * 8 + (K & 7)] = f2bf(f);
}

// ---------------- kernel 3: fused gather + MFMA GEMM -------------------------
__global__ __launch_bounds__(256) void sphconv_kernel(
    const float* __restrict__ x, const short* __restrict__ wbf,
    const float* __restrict__ bias, const Desc* __restrict__ desc,
    float* __restrict__ out) {
  __shared__ __align__(16) short Wl[8 * COUT * 8];  // [kg][co][j]  16 KB
  __shared__ __align__(16) short Sl[8 * PXT * 8];   // [kg][px][j]   8 KB

  const int tid  = threadIdx.x;
  const int ct   = blockIdx.x;          // 0..3
  const int r    = blockIdx.y;          // 0..127
  const int n    = blockIdx.z;          // 0..3
  const int c0   = ct * PXT;
  const int lane = tid & 63;
  const int wv   = tid >> 6;
  const int co_base = (wv & 1) * 64;
  const int px_base = (wv >> 1) * 32;

  // Load owned descriptors into registers (each thread owns 2-3 of 576).
  Desc dloc[3];
  int dk[3], dpx[3];
  int nd = 0;
  const Desc* dbase = desc + ((size_t)r * IMW + c0) * 9;
  for (int d = tid; d < KTOT; d += 256) {
    dloc[nd] = dbase[d];
    dpx[nd]  = d / 9;
    dk[nd]   = d - dpx[nd] * 9;
    nd++;
  }

  floatx4 acc[4][2];
  #pragma unroll
  for (int mt = 0; mt < 4; mt++)
    #pragma unroll
    for (int nt = 0; nt < 2; nt++)
      acc[mt][nt] = (floatx4){0.f, 0.f, 0.f, 0.f};

  const float* xn = x + (size_t)n * CIN * IMH * IMW;

  for (int cb = 0; cb < 9; cb++) {
    __syncthreads();   // previous chunk's MFMA reads done before overwrite
    // stage weight chunk: 16 KB contiguous
    {
      const uint4* src = (const uint4*)(wbf + cb * (KC * COUT / 8) * 8);
      uint4* dst = (uint4*)Wl;
      #pragma unroll
      for (int t = 0; t < 4; t++) dst[tid + t * 256] = src[tid + t * 256];
    }
    // gather samples for K in [cb*64, cb*64+64)
    const int kb = cb * KC;
    for (int dd = 0; dd < nd; dd++) {
      const int k  = dk[dd];
      const int px = dpx[dd];
      int ci_lo = (kb - k + 8) / 9;                 // numerator always >= 0
      int ci_hi = (kb + (KC - 1) - k) / 9 + 1;
      if (ci_hi > CIN) ci_hi = CIN;
      const Desc D = dloc[dd];
      for (int ci = ci_lo; ci < ci_hi; ci++) {
        const int kk = ci * 9 + k - kb;             // 0..63
        const float* xp = xn + (ci << 15);          // IMH*IMW = 32768
        float s = D.w00 * xp[D.o00] + D.w01 * xp[D.o01]
                + D.w10 * xp[D.o10] + D.w11 * xp[D.o11];
        Sl[((kk >> 3) * PXT + px) * 8 + (kk & 7)] = f2bf(s);
      }
    }
    __syncthreads();
    // MFMA over this chunk: 2 K-steps of 32
    #pragma unroll
    for (int ks = 0; ks < 2; ks++) {
      const int kg = ks * 4 + (lane >> 4);
      short8 a[4], b[2];
      #pragma unroll
      for (int mt = 0; mt < 4; mt++)
        a[mt] = *(const short8*)&Wl[((kg * COUT) + co_base + mt * 16 + (lane & 15)) * 8];
      #pragma unroll
      for (int nt = 0; nt < 2; nt++)
        b[nt] = *(const short8*)&Sl[((kg * PXT) + px_base + nt * 16 + (lane & 15)) * 8];
      #pragma unroll
      for (int mt = 0; mt < 4; mt++)
        #pragma unroll
        for (int nt = 0; nt < 2; nt++)
          acc[mt][nt] = __builtin_amdgcn_mfma_f32_16x16x32_bf16(a[mt], b[nt], acc[mt][nt], 0, 0, 0);
    }
  }

  // epilogue: D[row=co][col=px], row=(lane>>4)*4+reg, col=lane&15
  #pragma unroll
  for (int mt = 0; mt < 4; mt++) {
    #pragma unroll
    for (int nt = 0; nt < 2; nt++) {
      #pragma unroll
      for (int rg = 0; rg < 4; rg++) {
        const int co = co_base + mt * 16 + (lane >> 4) * 4 + rg;
        const int c  = c0 + px_base + nt * 16 + (lane & 15);
        out[(((size_t)n * COUT + co) * IMH + r) * IMW + c] = acc[mt][nt][rg] + bias[co];
      }
    }
  }
}

extern "C" void kernel_launch(void* const* d_in, const int* in_sizes, int n_in,
                              void* d_out, int out_size, void* d_ws, size_t ws_size,
                              hipStream_t stream) {
  const float* x    = (const float*)d_in[0];
  const float* w    = (const float*)d_in[1];
  const float* bias = (const float*)d_in[2];
  float* out = (float*)d_out;
  Desc*  desc = (Desc*)d_ws;                                   // 9.44 MB
  short* wbf  = (short*)((char*)d_ws + (size_t)NDESC * sizeof(Desc));  // +147 KB
  (void)in_sizes; (void)n_in; (void)out_size; (void)ws_size;

  hipLaunchKernelGGL(gen_desc_kernel, dim3((NDESC + 255) / 256), dim3(256), 0, stream, desc);
  hipLaunchKernelGGL(prep_w_kernel, dim3((COUT * KTOT + 255) / 256), dim3(256), 0, stream, w, wbf);
  hipLaunchKernelGGL(sphconv_kernel, dim3(IMW / PXT, IMH, NB), dim3(256), 0, stream,
                     x, wbf, bias, desc, out);
}

// Round 3
// 254.683 us; speedup vs baseline: 1.7419x; 1.7419x over previous
//
#include <hip/hip_runtime.h>
#include <math.h>

typedef __attribute__((ext_vector_type(8))) short short8;
typedef __attribute__((ext_vector_type(4))) float floatx4;

#define NB    4
#define CIN   64
#define COUT  128
#define IMH   128
#define IMW   256
#define KTOT  576
#define NPIX  (IMH * IMW)
#define PXT   128
#define NDPB  (PXT * 9)          // 1152 descriptors per block
#define STG_ROW  134             // words per staged row (128 data + pad)
#define STG_COPY (5 * STG_ROW)   // 670
#define STG_CH   (2 * STG_COPY)  // 1340 words per channel

// 20B descriptor: packed pair-word offsets + 4 fully-masked weights
struct __align__(4) DescP { int o_pack; float w0, w1, w2, w3; };

__device__ __forceinline__ unsigned short f2bf(float f) {
  union { float f; unsigned u; } v; v.f = f;
  return (unsigned short)((v.u + 0x7FFFu + ((v.u >> 16) & 1u)) >> 16);
}
__device__ __forceinline__ unsigned pk2(float lo, float hi) {
  return (unsigned)f2bf(lo) | ((unsigned)f2bf(hi) << 16);
}
__device__ __forceinline__ float bfl(unsigned w) {
  union { unsigned u; float f; } v; v.u = w << 16; return v.f;
}
__device__ __forceinline__ float bfh(unsigned w) {
  union { unsigned u; float f; } v; v.u = w & 0xFFFF0000u; return v.f;
}

// ---------------- kernel 1: grid -> pair-packed bilinear descriptors --------
__global__ __launch_bounds__(256) void gen_desc_kernel(DescP* __restrict__ desc) {
  int idx = blockIdx.x * 256 + threadIdx.x;   // one thread per (r,c)
  if (idx >= NPIX) return;
  int c = idx & (IMW - 1), r = idx >> 8;
  const double pi = 3.14159265358979323846;
  double dphi = pi / IMH;
  double dth  = 2.0 * pi / IMW;
  double t  = tan(dth);
  double p  = tan(dphi);
  double sp = p / cos(dth);
  double phi   = -(((double)r + 0.5) / IMH * pi - pi * 0.5);
  double theta = ((double)c + 0.5) / IMW * (2.0 * pi) - pi;
  double sphi = sin(phi), cphi = cos(phi);
  int rlo = min(max(r - 2, 0), IMH - 5);

  for (int k = 0; k < 9; k++) {
    int i = k / 3, j = k % 3;
    double new_r, new_c;
    if (k == 4) {
      new_r = (double)r; new_c = (double)c;
    } else {
      double X = (j == 0) ? -t : ((j == 2) ? t : 0.0);
      double Y = 0.0;
      if (i == 0)      Y = (j == 1) ?  p :  sp;
      else if (i == 2) Y = (j == 1) ? -p : -sp;
      double rho = sqrt(X * X + Y * Y);
      double v   = atan(rho);
      double sv = sin(v), cv = cos(v);
      double arg = cv * sphi + Y * sv * cphi / rho;
      arg = fmin(1.0, fmax(-1.0, arg));
      double new_phi = asin(arg);
      double denom = rho * cphi * cv - Y * sphi * sv;
      double new_theta = theta + atan(X * sv / denom);
      new_r = (-new_phi + pi * 0.5) * IMH / pi - 0.5;
      new_c = (new_theta + pi) * IMW / (2.0 * pi) - 0.5;
      new_c = fmod(new_c + (double)IMW, (double)IMW);
    }
    // exact reference roundtrip: f64 -> f32 grid -> f32 unnormalize
    float gx = (float)(new_c * 2.0 / IMW - 1.0);
    float gy = (float)(new_r * 2.0 / IMH - 1.0);
    float ix = ((gx + 1.0f) * (float)IMW - 1.0f) * 0.5f;
    float iy = ((gy + 1.0f) * (float)IMH - 1.0f) * 0.5f;
    float fx = floorf(ix), fy = floorf(iy);
    int x0 = (int)fx, y0 = (int)fy;
    float wx1 = ix - fx, wy1 = iy - fy;
    float wx0 = 1.0f - wx1, wy0 = 1.0f - wy1;
    int x1 = x0 + 1, y1 = y0 + 1;
    bool vx0 = (x0 >= 0) & (x0 <= IMW - 1);
    bool vx1 = (x1 >= 0) & (x1 <= IMW - 1);
    bool vy0 = (y0 >= 0) & (y0 <= IMH - 1);
    bool vy1 = (y1 >= 0) & (y1 <= IMH - 1);
    int y0c = min(max(y0, 0), IMH - 1), y1c = min(max(y1, 0), IMH - 1);
    // column pair-word selection (copy 0 = even-based pairs, copy 1 = odd-based)
    int copy, widx;
    if (x0 < 0)        { copy = 0; widx = 0; }
    else if (x0 & 1)   { copy = 1; widx = (x0 - 1) >> 1; }
    else               { copy = 0; widx = x0 >> 1; }
    int col_lo = 2 * widx + copy;
    int col_hi = col_lo + 1;
    float wl = (col_lo == x0 && vx0) ? wx0 : ((col_lo == x1 && vx1) ? wx1 : 0.0f);
    float wh = (col_hi == x0 && vx0) ? wx0 : ((col_hi == x1 && vx1) ? wx1 : 0.0f);
    float wy0m = vy0 ? wy0 : 0.0f, wy1m = vy1 ? wy1 : 0.0f;
    int o_top = copy * STG_COPY + (y0c - rlo) * STG_ROW + widx;
    int o_bot = copy * STG_COPY + (y1c - rlo) * STG_ROW + widx;
    DescP d;
    d.o_pack = o_top | (o_bot << 16);
    d.w0 = wy0m * wl; d.w1 = wy0m * wh;
    d.w2 = wy1m * wl; d.w3 = wy1m * wh;
    desc[idx * 9 + k] = d;
  }
}

// ---------------- kernel 2: weight fp32 [co][K] -> bf16 [K/8][co][8] --------
__global__ __launch_bounds__(256) void prep_w_kernel(const float* __restrict__ w,
                                                     unsigned short* __restrict__ wbf) {
  int idx = blockIdx.x * 256 + threadIdx.x;
  if (idx >= COUT * KTOT) return;
  int co = idx / KTOT;
  int K  = idx - co * KTOT;
  wbf[(K >> 3) * (COUT * 8) + co * 8 + (K & 7)] = f2bf(w[co * KTOT + K]);
}

// ---------------- kernel 3: LDS-staged gather + MFMA GEMM -------------------
__global__ __launch_bounds__(256, 2) void sphconv_kernel(
    const float* __restrict__ x, const unsigned short* __restrict__ wbf,
    const float* __restrict__ bias, const DescP* __restrict__ desc,
    float* __restrict__ out) {
  __shared__ __align__(16) unsigned short Wl[8 * COUT * 8];  // 16 KB [kg][co][j]
  __shared__ __align__(16) unsigned short Sl[8 * PXT * 8];   // 16 KB [kg][px][j]
  __shared__ __align__(16) unsigned stg[4 * STG_CH];         // 21.4 KB bf16 pair-words

  const int tid  = threadIdx.x;
  const int ct   = blockIdx.x;          // 0..1
  const int r    = blockIdx.y;          // 0..127
  const int n    = blockIdx.z;          // 0..3
  const int c0   = ct * PXT;
  const int lane = tid & 63;
  const int wv   = tid >> 6;
  const int co_base = (wv & 1) * 64;
  const int px_base = (wv >> 1) * 64;
  const int rlo  = min(max(r - 2, 0), IMH - 5);

  // descriptor registers (4-5 per thread)
  int opk[5], dk_[5], dpx_[5];
  float w0[5], w1[5], w2[5], w3[5];
  const DescP* dbase = desc + ((size_t)r * IMW + c0) * 9;
  #pragma unroll
  for (int dd = 0; dd < 5; dd++) {
    int d = tid + dd * 256;
    if (d < NDPB) {
      DescP D = dbase[d];
      opk[dd] = D.o_pack;
      w0[dd] = D.w0; w1[dd] = D.w1; w2[dd] = D.w2; w3[dd] = D.w3;
      dpx_[dd] = d / 9; dk_[dd] = d - dpx_[dd] * 9;
    }
  }

  floatx4 acc[4][4];
  #pragma unroll
  for (int mt = 0; mt < 4; mt++)
    #pragma unroll
    for (int nt = 0; nt < 4; nt++)
      acc[mt][nt] = (floatx4){0.f, 0.f, 0.f, 0.f};

  const float* xn = x + (size_t)n * CIN * NPIX;

  #pragma unroll 1
  for (int cb = 0; cb < 9; cb++) {
    const int kb  = cb * 64;
    const int ci0 = kb / 9;
    __syncthreads();   // prev chunk's Wl/Sl reads + stg reads done
    { // stage weight chunk (16 KB contiguous)
      const uint4* src = (const uint4*)(wbf + cb * 8192);
      uint4* dst = (uint4*)Wl;
      #pragma unroll
      for (int t2 = 0; t2 < 4; t2++) dst[tid + t2 * 256] = src[tid + t2 * 256];
    }
    #pragma unroll 1
    for (int h = 0; h < 2; h++) {
      const int cA = ci0 + 4 * h;
      if (h) __syncthreads();      // gather(h=0) done reading stg
      { // stage channel cA+wv, rows rw 0..4 (bf16, two shifted pair-copies)
        const float* src = xn + (size_t)(cA + wv) * NPIX + (size_t)rlo * IMW + lane * 4;
        unsigned* dstA = &stg[wv * STG_CH];
        unsigned* dstB = &stg[wv * STG_CH + STG_COPY];
        #pragma unroll
        for (int rw = 0; rw < 5; rw++) {
          float4 v = *(const float4*)(src + rw * IMW);
          // col 4*lane+4 (lane<63 only; for lane 63 that word's hi half is the
          // never-used col-256 slot -> 0). Guarded: unguarded read would step
          // 1 element past x for the last channel/batch.
          float c4 = 0.0f;
          if (lane < 63) c4 = src[rw * IMW + 4];
          uint2 wa; wa.x = pk2(v.x, v.y); wa.y = pk2(v.z, v.w);
          uint2 wb; wb.x = pk2(v.y, v.z); wb.y = pk2(v.w, c4);
          *(uint2*)&dstA[rw * STG_ROW + 2 * lane] = wa;
          *(uint2*)&dstB[rw * STG_ROW + 2 * lane] = wb;
        }
      }
      __syncthreads();             // stg half ready
      // gather this half's channels into Sl
      #pragma unroll
      for (int dd = 0; dd < 5; dd++) {
        int d = tid + dd * 256;
        if (d < NDPB) {
          const int k = dk_[dd], px = dpx_[dd];
          int ci_lo = (kb - k + 8) / 9;
          int ci_hi = (kb + 63 - k) / 9 + 1; if (ci_hi > CIN) ci_hi = CIN;
          const unsigned* ptop = &stg[opk[dd] & 0xFFFF];
          const unsigned* pbot = &stg[((unsigned)opk[dd]) >> 16];
          #pragma unroll
          for (int chl = 0; chl < 4; chl++) {
            int ci = cA + chl;
            if (ci >= ci_lo && ci < ci_hi) {
              unsigned wt  = ptop[chl * STG_CH];
              unsigned wb_ = pbot[chl * STG_CH];
              float s = w0[dd] * bfl(wt) + w1[dd] * bfh(wt)
                      + w2[dd] * bfl(wb_) + w3[dd] * bfh(wb_);
              int kk = ci * 9 + k - kb;   // 0..63
              Sl[((kk >> 3) * PXT + px) * 8 + (kk & 7)] = f2bf(s);
            }
          }
        }
      }
    }
    __syncthreads();   // Sl complete
    #pragma unroll
    for (int ks = 0; ks < 2; ks++) {
      const int kg = ks * 4 + (lane >> 4);
      short8 a[4], b[4];
      #pragma unroll
      for (int mt = 0; mt < 4; mt++)
        a[mt] = *(const short8*)&Wl[((kg * COUT) + co_base + mt * 16 + (lane & 15)) * 8];
      #pragma unroll
      for (int nt = 0; nt < 4; nt++)
        b[nt] = *(const short8*)&Sl[((kg * PXT) + px_base + nt * 16 + (lane & 15)) * 8];
      #pragma unroll
      for (int mt = 0; mt < 4; mt++)
        #pragma unroll
        for (int nt = 0; nt < 4; nt++)
          acc[mt][nt] = __builtin_amdgcn_mfma_f32_16x16x32_bf16(a[mt], b[nt], acc[mt][nt], 0, 0, 0);
    }
  }

  // epilogue: D row = co, col = px (row=(lane>>4)*4+reg, col=lane&15)
  #pragma unroll
  for (int mt = 0; mt < 4; mt++) {
    #pragma unroll
    for (int nt = 0; nt < 4; nt++) {
      #pragma unroll
      for (int rg = 0; rg < 4; rg++) {
        const int co = co_base + mt * 16 + (lane >> 4) * 4 + rg;
        const int cc = c0 + px_base + nt * 16 + (lane & 15);
        out[(((size_t)n * COUT + co) * IMH + r) * IMW + cc] = acc[mt][nt][rg] + bias[co];
      }
    }
  }
}

extern "C" void kernel_launch(void* const* d_in, const int* in_sizes, int n_in,
                              void* d_out, int out_size, void* d_ws, size_t ws_size,
                              hipStream_t stream) {
  const float* x    = (const float*)d_in[0];
  const float* w    = (const float*)d_in[1];
  const float* bias = (const float*)d_in[2];
  float* out = (float*)d_out;
  DescP* desc = (DescP*)d_ws;                                       // 5.9 MB
  unsigned short* wbf = (unsigned short*)((char*)d_ws + (size_t)NPIX * 9 * sizeof(DescP));
  (void)in_sizes; (void)n_in; (void)out_size; (void)ws_size;

  hipLaunchKernelGGL(gen_desc_kernel, dim3(NPIX / 256), dim3(256), 0, stream, desc);
  hipLaunchKernelGGL(prep_w_kernel, dim3((COUT * KTOT + 255) / 256), dim3(256), 0, stream, w, wbf);
  hipLaunchKernelGGL(sphconv_kernel, dim3(IMW / PXT, IMH, NB), dim3(256), 0, stream,
                     x, wbf, bias, desc, out);
}